// Round 9
// baseline (112.542 us; speedup 1.0000x reference)
//
#include <hip/hip_runtime.h>

#define NPTS 262144
#define HP1 2654435761u
#define HP2 805459861u
#define TMASK 0x7FFFFu

typedef __attribute__((ext_vector_type(8))) short short8;
typedef __attribute__((ext_vector_type(4))) float f32x4;
typedef unsigned short ushort_t;
typedef unsigned int uint_t;

#define MFMA(a, b, c) __builtin_amdgcn_mfma_f32_16x16x32_bf16((a), (b), (c), 0, 0, 0)

__device__ __forceinline__ ushort_t f2bf(float f) {
    uint_t u = __float_as_uint(f);
    return (ushort_t)((u + 0x7FFFu + ((u >> 16) & 1u)) >> 16);
}
__device__ __forceinline__ float sigmoidf_fast(float v) {
    return 1.0f / (1.0f + __expf(-v));
}

// Dense re-layout for levels 0..4 (dims 17,23,31,43,59), 16B/entry (both x-corners).
#define DOFF0 0
#define DOFF1 4913
#define DOFF2 17080
#define DOFF3 46871
#define DOFF4 126378
#define DTOT  331757

// ws layout (bytes): [0,16MB) feats, [16MB,+5.31MB) dense, [22MB,+24KB) weight frags
#define WS_DN_OFF (16u * 1024u * 1024u)
#define WS_WF_OFF (22u * 1024u * 1024u)

// Weight-fragment offsets (ushort elements)
#define OFF_DW1 0
#define OFF_DW2 2048
#define OFF_CW1 3072
#define OFF_CW2 7168
#define OFF_CW3 11264
#define WF_TOTAL 12288

// ---------------- Kernel 0a: pack weights into bf16 MFMA B-fragments ----------------
extern "C" __global__ void ngp_prep(
    const float* __restrict__ dW1, const float* __restrict__ dW2,
    const float* __restrict__ cW1, const float* __restrict__ cW2,
    const float* __restrict__ cW3, ushort_t* __restrict__ wf)
{
    const int e = blockIdx.x * 256 + (int)threadIdx.x;
    if (e >= WF_TOTAL) return;
    const float* W; int base, NT, KR, NR;
    if (e < OFF_DW2)      { W = dW1; base = OFF_DW1; NT = 4; KR = 32; NR = 64; }
    else if (e < OFF_CW1) { W = dW2; base = OFF_DW2; NT = 1; KR = 64; NR = 16; }
    else if (e < OFF_CW2) { W = cW1; base = OFF_CW1; NT = 4; KR = 43; NR = 64; }
    else if (e < OFF_CW3) { W = cW2; base = OFF_CW2; NT = 4; KR = 64; NR = 64; }
    else                  { W = cW3; base = OFF_CW3; NT = 1; KR = 64; NR = 3;  }
    const int r = e - base;
    const int frag = r >> 9;
    const int lane = (r >> 3) & 63;
    const int j = r & 7;
    const int kc = frag / NT, nt = frag % NT;
    const int k = kc * 32 + ((lane >> 4) << 3) + j;
    const int n = nt * 16 + (lane & 15);
    const float v = (k < KR && n < NR) ? W[k * NR + n] : 0.0f;
    wf[e] = f2bf(v);
}

// ---------------- Kernel 0b: densify levels 0..4 ----------------
extern "C" __global__ void ngp_dense(
    const float* __restrict__ tbl, f32x4* __restrict__ dense)
{
    const int e = blockIdx.x * 256 + (int)threadIdx.x;
    if (e >= DTOT) return;
    int l, base, dim;
    if (e < DOFF1)      { l = 0; base = DOFF0; dim = 17; }
    else if (e < DOFF2) { l = 1; base = DOFF1; dim = 23; }
    else if (e < DOFF3) { l = 2; base = DOFF2; dim = 31; }
    else if (e < DOFF4) { l = 3; base = DOFF3; dim = 43; }
    else                { l = 4; base = DOFF4; dim = 59; }
    const int r = e - base;
    const int v0 = r % dim;
    const int t  = r / dim;
    const int v1 = t % dim;
    const int v2 = t / dim;
    const float2* tp = (const float2*)tbl + ((size_t)l << 19);
    const unsigned hy = (unsigned)v1 * HP1;
    const unsigned hz = (unsigned)v2 * HP2;
    const unsigned h0 = ((unsigned)v0 ^ hy ^ hz) & TMASK;
    const unsigned h1 = (((unsigned)v0 + 1u) ^ hy ^ hz) & TMASK;
    const float2 c0 = tp[h0];
    const float2 c1 = tp[h1];
    dense[e] = (f32x4){c0.x, c0.y, c1.x, c1.y};
}

// ---------------- Kernel A: hash-grid encode ----------------
// grid = 16 levels x 1024 blocks; level uniform per block; 1 point/thread.
// Levels 0..4: dense array, 4 x 16B loads.
// Levels 5..15: even-v0 lanes use 4 x 16B paired loads (h(v0+1)=h(v0)^1 shares
// a 16B-aligned block); odd-v0 lanes fall back to 8 x 8B gathers.
extern "C" __global__ void __launch_bounds__(256) ngp_encode(
    const float* __restrict__ xin, const float* __restrict__ tbl,
    const f32x4* __restrict__ dense, uint_t* __restrict__ feats)
{
    const int b  = blockIdx.x;
    const int l  = b >> 10;
    const int pt = ((b & 1023) << 8) + (int)threadIdx.x;

    static const float NLs[16] = {16.f, 22.f, 30.f, 42.f, 58.f, 80.f, 111.f, 153.f,
                                  212.f, 294.f, 406.f, 561.f, 776.f, 1072.f, 1482.f, 2048.f};
    static const int DDIM[5] = {17, 23, 31, 43, 59};
    static const int DOFFS[5] = {DOFF0, DOFF1, DOFF2, DOFF3, DOFF4};

    const float x0 = xin[3 * pt + 0];
    const float x1 = xin[3 * pt + 1];
    const float x2 = xin[3 * pt + 2];
    const bool msk = (fabsf(x0) < 1.5f) & (fabsf(x1) < 1.5f) & (fabsf(x2) < 1.5f);
    if (!msk) return;

    const float nl = NLs[l];
    const float s0 = (x0 / 3.0f + 0.5f) * nl;
    const float s1 = (x1 / 3.0f + 0.5f) * nl;
    const float s2 = (x2 / 3.0f + 0.5f) * nl;
    const float f0 = floorf(s0), f1 = floorf(s1), f2 = floorf(s2);
    const float l0 = s0 - f0, l1 = s1 - f1, l2 = s2 - f2;
    const float m0 = 1.0f - l0, m1 = 1.0f - l1, m2 = 1.0f - l2;

    float a = 0.0f, bb = 0.0f;

    if (l < 5) {
        // ---------- dense path ----------
        const int dim = DDIM[l];
        const f32x4* dp = dense + DOFFS[l];
        const int idx = ((int)f2 * dim + (int)f1) * dim + (int)f0;
        const f32x4 C00 = dp[idx];
        const f32x4 C10 = dp[idx + dim];
        const f32x4 C01 = dp[idx + dim * dim];
        const f32x4 C11 = dp[idx + dim * dim + dim];
        float w;
        w = m1 * m2; a = fmaf(m0 * w, C00[0], a); bb = fmaf(m0 * w, C00[1], bb);
                     a = fmaf(l0 * w, C00[2], a); bb = fmaf(l0 * w, C00[3], bb);
        w = l1 * m2; a = fmaf(m0 * w, C10[0], a); bb = fmaf(m0 * w, C10[1], bb);
                     a = fmaf(l0 * w, C10[2], a); bb = fmaf(l0 * w, C10[3], bb);
        w = m1 * l2; a = fmaf(m0 * w, C01[0], a); bb = fmaf(m0 * w, C01[1], bb);
                     a = fmaf(l0 * w, C01[2], a); bb = fmaf(l0 * w, C01[3], bb);
        w = l1 * l2; a = fmaf(m0 * w, C11[0], a); bb = fmaf(m0 * w, C11[1], bb);
                     a = fmaf(l0 * w, C11[2], a); bb = fmaf(l0 * w, C11[3], bb);
    } else {
        // ---------- hash path ----------
        const float2* tp = (const float2*)tbl + ((size_t)l << 19);
        const f32x4* tp4 = (const f32x4*)tp;
        const unsigned v0 = (unsigned)(int)f0;
        const unsigned hy0 = (unsigned)(int)f1 * HP1, hy1 = hy0 + HP1;
        const unsigned hz0 = (unsigned)(int)f2 * HP2, hz1 = hz0 + HP2;
        unsigned hyz[4];
        hyz[0] = hy0 ^ hz0;   // (y0,z0)
        hyz[1] = hy1 ^ hz0;   // (y1,z0)
        hyz[2] = hy0 ^ hz1;   // (y0,z1)
        hyz[3] = hy1 ^ hz1;   // (y1,z1)

        float2 c[8];   // c[2j] = x-lo corner, c[2j+1] = x-hi corner for pair j
        if ((v0 & 1u) == 0u) {
            // even v0: both x-corners {h, h^1} share the 16B block h>>1
            #pragma unroll
            for (int j = 0; j < 4; ++j) {
                const unsigned hp = (v0 ^ hyz[j]) & TMASK;
                const f32x4 blk = tp4[hp >> 1];
                const float2 lo = {blk[0], blk[1]};
                const float2 hi = {blk[2], blk[3]};
                const bool sw = (hp & 1u) != 0u;   // hp odd -> c(v0) is hi half
                c[2 * j + 0] = sw ? hi : lo;
                c[2 * j + 1] = sw ? lo : hi;
            }
        } else {
            const unsigned vb0 = v0 + 1u;
            #pragma unroll
            for (int j = 0; j < 4; ++j) {
                c[2 * j + 0] = tp[(v0  ^ hyz[j]) & TMASK];
                c[2 * j + 1] = tp[(vb0 ^ hyz[j]) & TMASK];
            }
        }
        float w;
        w = m1 * m2; a = fmaf(m0 * w, c[0].x, a); bb = fmaf(m0 * w, c[0].y, bb);
                     a = fmaf(l0 * w, c[1].x, a); bb = fmaf(l0 * w, c[1].y, bb);
        w = l1 * m2; a = fmaf(m0 * w, c[2].x, a); bb = fmaf(m0 * w, c[2].y, bb);
                     a = fmaf(l0 * w, c[3].x, a); bb = fmaf(l0 * w, c[3].y, bb);
        w = m1 * l2; a = fmaf(m0 * w, c[4].x, a); bb = fmaf(m0 * w, c[4].y, bb);
                     a = fmaf(l0 * w, c[5].x, a); bb = fmaf(l0 * w, c[5].y, bb);
        w = l1 * l2; a = fmaf(m0 * w, c[6].x, a); bb = fmaf(m0 * w, c[6].y, bb);
                     a = fmaf(l0 * w, c[7].x, a); bb = fmaf(l0 * w, c[7].y, bb);
    }

    feats[(size_t)l * NPTS + pt] = (uint_t)f2bf(a) | ((uint_t)f2bf(bb) << 16);
}

// ---------------- Kernel B: MFMA MLPs (R3-verified) ----------------
extern "C" __global__ void __launch_bounds__(256) ngp_mlp(
    const float* __restrict__ xin, const float* __restrict__ din,
    const uint_t* __restrict__ featsbf, const ushort_t* __restrict__ wf,
    const float* __restrict__ db1, const float* __restrict__ db2,
    const float* __restrict__ cb1, const float* __restrict__ cb2,
    const float* __restrict__ cb3,
    float* __restrict__ out)
{
    __shared__ short act[4][4096];
    __shared__ float mk[4][64];

    const int w    = (int)threadIdx.x >> 6;
    const int lane = (int)threadIdx.x & 63;
    const int lrow = lane & 15;
    const int lq   = lane >> 4;
    const int ptb  = blockIdx.x * 256 + w * 64;
    const int p    = ptb + lane;
    char* Ab = (char*)&act[w][0];

#define LDSA(mt, kc) (*reinterpret_cast<const short8*>(Ab + ((((mt) * 16 + lrow) * 128 + (kc) * 64 + lq * 16) ^ ((lrow & 7) << 4))))
#define LOADB(off)   (*reinterpret_cast<const short8*>(wf + (off) + lane * 8))
#define STB16(row, col, val) *reinterpret_cast<ushort_t*>(Ab + ((((row) * 128 + (col) * 2)) ^ (((row) & 7) << 4))) = (val)

    const float x0 = xin[3 * p + 0];
    const float x1 = xin[3 * p + 1];
    const float x2 = xin[3 * p + 2];
    const bool msk = (fabsf(x0) < 1.5f) & (fabsf(x1) < 1.5f) & (fabsf(x2) < 1.5f);
    mk[w][lane] = msk ? 1.0f : 0.0f;

    uint_t u[16];
    #pragma unroll
    for (int l = 0; l < 16; ++l) u[l] = featsbf[(size_t)l * NPTS + p];
    #pragma unroll
    for (int c = 0; c < 4; ++c) {
        short8 v;
        #pragma unroll
        for (int q = 0; q < 4; ++q) {
            v[2 * q + 0] = (short)(u[4 * c + q] & 0xFFFFu);
            v[2 * q + 1] = (short)(u[4 * c + q] >> 16);
        }
        const int byte = (lane * 128 + 16 * c) ^ ((lane & 7) << 4);
        *reinterpret_cast<short8*>(Ab + byte) = v;
    }
    const float d0v = din[3 * p + 0];
    const float d1v = din[3 * p + 1];
    const float d2v = din[3 * p + 2];

    __syncthreads();

    // ---- Layer D1: feats[64x32] @ dW1[32x64] ----
    f32x4 acc[4][4];
    #pragma unroll
    for (int nt = 0; nt < 4; ++nt) {
        const float b = db1[nt * 16 + lrow];
        #pragma unroll
        for (int mt = 0; mt < 4; ++mt) acc[mt][nt] = (f32x4){b, b, b, b};
    }
    {
        short8 a0 = LDSA(0, 0), a1 = LDSA(1, 0), a2 = LDSA(2, 0), a3 = LDSA(3, 0);
        #pragma unroll
        for (int nt = 0; nt < 4; ++nt) {
            const short8 B = LOADB(OFF_DW1 + nt * 512);
            acc[0][nt] = MFMA(a0, B, acc[0][nt]);
            acc[1][nt] = MFMA(a1, B, acc[1][nt]);
            acc[2][nt] = MFMA(a2, B, acc[2][nt]);
            acc[3][nt] = MFMA(a3, B, acc[3][nt]);
        }
    }
    __syncthreads();
    #pragma unroll
    for (int mt = 0; mt < 4; ++mt)
        #pragma unroll
        for (int nt = 0; nt < 4; ++nt)
            #pragma unroll
            for (int r = 0; r < 4; ++r) {
                const int row = mt * 16 + lq * 4 + r;
                STB16(row, nt * 16 + lrow, f2bf(fmaxf(acc[mt][nt][r], 0.0f)));
            }
    __syncthreads();

    // ---- Layer D2: hid[64x64] @ dW2[64x16] ----
    f32x4 hD[4];
    {
        const float b = db2[lrow];
        #pragma unroll
        for (int mt = 0; mt < 4; ++mt) hD[mt] = (f32x4){b, b, b, b};
        #pragma unroll
        for (int kc = 0; kc < 2; ++kc) {
            const short8 B = LOADB(OFF_DW2 + kc * 512);
            #pragma unroll
            for (int mt = 0; mt < 4; ++mt) hD[mt] = MFMA(LDSA(mt, kc), B, hD[mt]);
        }
    }
    __syncthreads();

    if (lrow == 0) {
        #pragma unroll
        for (int mt = 0; mt < 4; ++mt)
            #pragma unroll
            for (int r = 0; r < 4; ++r) {
                const int row = mt * 16 + lq * 4 + r;
                const float mm = mk[w][row];
                out[3 * NPTS + ptb + row] = (mm != 0.0f) ? __expf(hD[mt][r]) : 0.0f;
            }
    }
    #pragma unroll
    for (int mt = 0; mt < 4; ++mt)
        #pragma unroll
        for (int r = 0; r < 4; ++r) {
            const int row = mt * 16 + lq * 4 + r;
            STB16(row, lrow, f2bf(hD[mt][r]));
        }
    {
        ushort_t t[48];
        t[0] = f2bf(d0v); t[1] = f2bf(d1v); t[2] = f2bf(d2v);
        #pragma unroll
        for (int j = 0; j < 4; ++j) {
            const float s = (float)(1 << j);
            t[3 + 6 * j + 0] = f2bf(__sinf(s * d0v));
            t[3 + 6 * j + 1] = f2bf(__sinf(s * d1v));
            t[3 + 6 * j + 2] = f2bf(__sinf(s * d2v));
            t[3 + 6 * j + 3] = f2bf(__cosf(s * d0v));
            t[3 + 6 * j + 4] = f2bf(__cosf(s * d1v));
            t[3 + 6 * j + 5] = f2bf(__cosf(s * d2v));
        }
        #pragma unroll
        for (int i = 27; i < 48; ++i) t[i] = 0;
        #pragma unroll
        for (int c = 0; c < 6; ++c) {
            short8 v;
            #pragma unroll
            for (int j = 0; j < 8; ++j) v[j] = (short)t[8 * c + j];
            const int byte = (lane * 128 + 32 + 16 * c) ^ ((lane & 7) << 4);
            *reinterpret_cast<short8*>(Ab + byte) = v;
        }
    }
    __syncthreads();

    // ---- Layer C1: ch[64x64(43)] @ cW1[64x64] ----
    #pragma unroll
    for (int nt = 0; nt < 4; ++nt) {
        const float b = cb1[nt * 16 + lrow];
        #pragma unroll
        for (int mt = 0; mt < 4; ++mt) acc[mt][nt] = (f32x4){b, b, b, b};
    }
    #pragma unroll
    for (int kc = 0; kc < 2; ++kc) {
        short8 a0 = LDSA(0, kc), a1 = LDSA(1, kc), a2 = LDSA(2, kc), a3 = LDSA(3, kc);
        #pragma unroll
        for (int nt = 0; nt < 4; ++nt) {
            const short8 B = LOADB(OFF_CW1 + (kc * 4 + nt) * 512);
            acc[0][nt] = MFMA(a0, B, acc[0][nt]);
            acc[1][nt] = MFMA(a1, B, acc[1][nt]);
            acc[2][nt] = MFMA(a2, B, acc[2][nt]);
            acc[3][nt] = MFMA(a3, B, acc[3][nt]);
        }
    }
    __syncthreads();
    #pragma unroll
    for (int mt = 0; mt < 4; ++mt)
        #pragma unroll
        for (int nt = 0; nt < 4; ++nt)
            #pragma unroll
            for (int r = 0; r < 4; ++r) {
                const int row = mt * 16 + lq * 4 + r;
                STB16(row, nt * 16 + lrow, f2bf(fmaxf(acc[mt][nt][r], 0.0f)));
            }
    __syncthreads();

    // ---- Layer C2: c1[64x64] @ cW2[64x64] ----
    #pragma unroll
    for (int nt = 0; nt < 4; ++nt) {
        const float b = cb2[nt * 16 + lrow];
        #pragma unroll
        for (int mt = 0; mt < 4; ++mt) acc[mt][nt] = (f32x4){b, b, b, b};
    }
    #pragma unroll
    for (int kc = 0; kc < 2; ++kc) {
        short8 a0 = LDSA(0, kc), a1 = LDSA(1, kc), a2 = LDSA(2, kc), a3 = LDSA(3, kc);
        #pragma unroll
        for (int nt = 0; nt < 4; ++nt) {
            const short8 B = LOADB(OFF_CW2 + (kc * 4 + nt) * 512);
            acc[0][nt] = MFMA(a0, B, acc[0][nt]);
            acc[1][nt] = MFMA(a1, B, acc[1][nt]);
            acc[2][nt] = MFMA(a2, B, acc[2][nt]);
            acc[3][nt] = MFMA(a3, B, acc[3][nt]);
        }
    }
    __syncthreads();
    #pragma unroll
    for (int mt = 0; mt < 4; ++mt)
        #pragma unroll
        for (int nt = 0; nt < 4; ++nt)
            #pragma unroll
            for (int r = 0; r < 4; ++r) {
                const int row = mt * 16 + lq * 4 + r;
                STB16(row, nt * 16 + lrow, f2bf(fmaxf(acc[mt][nt][r], 0.0f)));
            }
    __syncthreads();

    // ---- Layer C3: c2[64x64] @ cW3[64x3(pad16)] ----
    f32x4 rD[4];
    {
        const float b = (lrow < 3) ? cb3[lrow] : 0.0f;
        #pragma unroll
        for (int mt = 0; mt < 4; ++mt) rD[mt] = (f32x4){b, b, b, b};
        #pragma unroll
        for (int kc = 0; kc < 2; ++kc) {
            const short8 B = LOADB(OFF_CW3 + kc * 512);
            #pragma unroll
            for (int mt = 0; mt < 4; ++mt) rD[mt] = MFMA(LDSA(mt, kc), B, rD[mt]);
        }
    }
    if (lrow < 3) {
        #pragma unroll
        for (int mt = 0; mt < 4; ++mt)
            #pragma unroll
            for (int r = 0; r < 4; ++r) {
                const int row = mt * 16 + lq * 4 + r;
                const float mm = mk[w][row];
                out[3 * (ptb + row) + lrow] = (mm != 0.0f) ? sigmoidf_fast(rD[mt][r]) : 0.0f;
            }
    }
#undef LDSA
#undef LOADB
#undef STB16
}

extern "C" void kernel_launch(void* const* d_in, const int* in_sizes, int n_in,
                              void* d_out, int out_size, void* d_ws, size_t ws_size,
                              hipStream_t stream) {
    const float* x    = (const float*)d_in[0];
    const float* d    = (const float*)d_in[1];
    const float* tbl  = (const float*)d_in[2];
    const float* dW1  = (const float*)d_in[3];
    const float* db1  = (const float*)d_in[4];
    const float* dW2  = (const float*)d_in[5];
    const float* db2  = (const float*)d_in[6];
    const float* cW1  = (const float*)d_in[7];
    const float* cb1  = (const float*)d_in[8];
    const float* cW2  = (const float*)d_in[9];
    const float* cb2  = (const float*)d_in[10];
    const float* cW3  = (const float*)d_in[11];
    const float* cb3  = (const float*)d_in[12];

    uint_t* feats = (uint_t*)d_ws;                               // 16 MB
    f32x4* dense  = (f32x4*)((char*)d_ws + WS_DN_OFF);           // 5.31 MB
    ushort_t* wfr = (ushort_t*)((char*)d_ws + WS_WF_OFF);        // 24 KB

    ngp_prep<<<48, 256, 0, stream>>>(dW1, dW2, cW1, cW2, cW3, wfr);
    ngp_dense<<<(DTOT + 255) / 256, 256, 0, stream>>>(tbl, dense);
    ngp_encode<<<16 * 1024, 256, 0, stream>>>(x, tbl, dense, feats);
    ngp_mlp<<<NPTS / 256, 256, 0, stream>>>(
        x, d, feats, wfr, db1, db2, cb1, cb2, cb3, (float*)d_out);
}

// Round 10
// 108.257 us; speedup vs baseline: 1.0396x; 1.0396x over previous
//
#include <hip/hip_runtime.h>

#define NPTS 262144
#define HP1 2654435761u
#define HP2 805459861u
#define TMASK 0x7FFFFu

typedef __attribute__((ext_vector_type(8))) short short8;
typedef __attribute__((ext_vector_type(4))) float f32x4;
typedef unsigned short ushort_t;
typedef unsigned int uint_t;

#define MFMA(a, b, c) __builtin_amdgcn_mfma_f32_16x16x32_bf16((a), (b), (c), 0, 0, 0)

__device__ __forceinline__ ushort_t f2bf(float f) {
    uint_t u = __float_as_uint(f);
    return (ushort_t)((u + 0x7FFFu + ((u >> 16) & 1u)) >> 16);
}
__device__ __forceinline__ float sigmoidf_fast(float v) {
    return 1.0f / (1.0f + __expf(-v));
}

// Dense re-layout for levels 0..4 (dims 17,23,31,43,59), 16B/entry (both x-corners).
#define DOFF0 0
#define DOFF1 4913
#define DOFF2 17080
#define DOFF3 46871
#define DOFF4 126378
#define DTOT  331757
#define DENSE_BLOCKS 1296   // ceil(DTOT/256)

// ws layout (bytes): [0,16MB) feats, [16MB,+5.31MB) dense, [22MB,+24KB) weight frags
#define WS_DN_OFF (16u * 1024u * 1024u)
#define WS_WF_OFF (22u * 1024u * 1024u)

// Weight-fragment offsets (ushort elements)
#define OFF_DW1 0
#define OFF_DW2 2048
#define OFF_CW1 3072
#define OFF_CW2 7168
#define OFF_CW3 11264
#define WF_TOTAL 12288
#define PREP_BLOCKS 48

// ---------------- Kernel 0: weight-frag pack + dense levels (merged) ----------------
extern "C" __global__ void ngp_predense(
    const float* __restrict__ dW1, const float* __restrict__ dW2,
    const float* __restrict__ cW1, const float* __restrict__ cW2,
    const float* __restrict__ cW3, ushort_t* __restrict__ wf,
    const float* __restrict__ tbl, f32x4* __restrict__ dense)
{
    if (blockIdx.x < PREP_BLOCKS) {
        const int e = blockIdx.x * 256 + (int)threadIdx.x;
        if (e >= WF_TOTAL) return;
        const float* W; int base, NT, KR, NR;
        if (e < OFF_DW2)      { W = dW1; base = OFF_DW1; NT = 4; KR = 32; NR = 64; }
        else if (e < OFF_CW1) { W = dW2; base = OFF_DW2; NT = 1; KR = 64; NR = 16; }
        else if (e < OFF_CW2) { W = cW1; base = OFF_CW1; NT = 4; KR = 43; NR = 64; }
        else if (e < OFF_CW3) { W = cW2; base = OFF_CW2; NT = 4; KR = 64; NR = 64; }
        else                  { W = cW3; base = OFF_CW3; NT = 1; KR = 64; NR = 3;  }
        const int r = e - base;
        const int frag = r >> 9;
        const int lane = (r >> 3) & 63;
        const int j = r & 7;
        const int kc = frag / NT, nt = frag % NT;
        const int k = kc * 32 + ((lane >> 4) << 3) + j;
        const int n = nt * 16 + (lane & 15);
        const float v = (k < KR && n < NR) ? W[k * NR + n] : 0.0f;
        wf[e] = f2bf(v);
        return;
    }
    const int e = (blockIdx.x - PREP_BLOCKS) * 256 + (int)threadIdx.x;
    if (e >= DTOT) return;
    int l, base, dim;
    if (e < DOFF1)      { l = 0; base = DOFF0; dim = 17; }
    else if (e < DOFF2) { l = 1; base = DOFF1; dim = 23; }
    else if (e < DOFF3) { l = 2; base = DOFF2; dim = 31; }
    else if (e < DOFF4) { l = 3; base = DOFF3; dim = 43; }
    else                { l = 4; base = DOFF4; dim = 59; }
    const int r = e - base;
    const int v0 = r % dim;
    const int t  = r / dim;
    const int v1 = t % dim;
    const int v2 = t / dim;
    const float2* tp = (const float2*)tbl + ((size_t)l << 19);
    const unsigned hy = (unsigned)v1 * HP1;
    const unsigned hz = (unsigned)v2 * HP2;
    const unsigned h0 = ((unsigned)v0 ^ hy ^ hz) & TMASK;
    const unsigned h1 = (((unsigned)v0 + 1u) ^ hy ^ hz) & TMASK;
    const float2 c0 = tp[h0];
    const float2 c1 = tp[h1];
    dense[e] = (f32x4){c0.x, c0.y, c1.x, c1.y};
}

// ---------------- Kernel A: hash-grid encode (R9-proven, ~80us floor) ----------------
extern "C" __global__ void __launch_bounds__(256) ngp_encode(
    const float* __restrict__ xin, const float* __restrict__ tbl,
    const f32x4* __restrict__ dense, uint_t* __restrict__ feats)
{
    const int b  = blockIdx.x;
    const int l  = b >> 10;
    const int pt = ((b & 1023) << 8) + (int)threadIdx.x;

    static const float NLs[16] = {16.f, 22.f, 30.f, 42.f, 58.f, 80.f, 111.f, 153.f,
                                  212.f, 294.f, 406.f, 561.f, 776.f, 1072.f, 1482.f, 2048.f};
    static const int DDIM[5] = {17, 23, 31, 43, 59};
    static const int DOFFS[5] = {DOFF0, DOFF1, DOFF2, DOFF3, DOFF4};

    const float x0 = xin[3 * pt + 0];
    const float x1 = xin[3 * pt + 1];
    const float x2 = xin[3 * pt + 2];
    const bool msk = (fabsf(x0) < 1.5f) & (fabsf(x1) < 1.5f) & (fabsf(x2) < 1.5f);
    if (!msk) return;

    const float nl = NLs[l];
    const float s0 = (x0 / 3.0f + 0.5f) * nl;
    const float s1 = (x1 / 3.0f + 0.5f) * nl;
    const float s2 = (x2 / 3.0f + 0.5f) * nl;
    const float f0 = floorf(s0), f1 = floorf(s1), f2 = floorf(s2);
    const float l0 = s0 - f0, l1 = s1 - f1, l2 = s2 - f2;
    const float m0 = 1.0f - l0, m1 = 1.0f - l1, m2 = 1.0f - l2;

    float a = 0.0f, bb = 0.0f;

    if (l < 5) {
        const int dim = DDIM[l];
        const f32x4* dp = dense + DOFFS[l];
        const int idx = ((int)f2 * dim + (int)f1) * dim + (int)f0;
        const f32x4 C00 = dp[idx];
        const f32x4 C10 = dp[idx + dim];
        const f32x4 C01 = dp[idx + dim * dim];
        const f32x4 C11 = dp[idx + dim * dim + dim];
        float w;
        w = m1 * m2; a = fmaf(m0 * w, C00[0], a); bb = fmaf(m0 * w, C00[1], bb);
                     a = fmaf(l0 * w, C00[2], a); bb = fmaf(l0 * w, C00[3], bb);
        w = l1 * m2; a = fmaf(m0 * w, C10[0], a); bb = fmaf(m0 * w, C10[1], bb);
                     a = fmaf(l0 * w, C10[2], a); bb = fmaf(l0 * w, C10[3], bb);
        w = m1 * l2; a = fmaf(m0 * w, C01[0], a); bb = fmaf(m0 * w, C01[1], bb);
                     a = fmaf(l0 * w, C01[2], a); bb = fmaf(l0 * w, C01[3], bb);
        w = l1 * l2; a = fmaf(m0 * w, C11[0], a); bb = fmaf(m0 * w, C11[1], bb);
                     a = fmaf(l0 * w, C11[2], a); bb = fmaf(l0 * w, C11[3], bb);
    } else {
        const float2* tp = (const float2*)tbl + ((size_t)l << 19);
        const unsigned va0 = (unsigned)(int)f0, vb0 = va0 + 1u;
        const unsigned va1 = (unsigned)(int)f1 * HP1, vb1 = va1 + HP1;
        const unsigned va2 = (unsigned)(int)f2 * HP2, vb2 = va2 + HP2;
        const float2 c0 = tp[(va0 ^ va1 ^ va2) & TMASK];
        const float2 c1 = tp[(vb0 ^ va1 ^ va2) & TMASK];
        const float2 c2 = tp[(va0 ^ vb1 ^ va2) & TMASK];
        const float2 c3 = tp[(vb0 ^ vb1 ^ va2) & TMASK];
        const float2 c4 = tp[(va0 ^ va1 ^ vb2) & TMASK];
        const float2 c5 = tp[(vb0 ^ va1 ^ vb2) & TMASK];
        const float2 c6 = tp[(va0 ^ vb1 ^ vb2) & TMASK];
        const float2 c7 = tp[(vb0 ^ vb1 ^ vb2) & TMASK];
        float w;
        w = m1 * m2; a = fmaf(m0 * w, c0.x, a); bb = fmaf(m0 * w, c0.y, bb);
                     a = fmaf(l0 * w, c1.x, a); bb = fmaf(l0 * w, c1.y, bb);
        w = l1 * m2; a = fmaf(m0 * w, c2.x, a); bb = fmaf(m0 * w, c2.y, bb);
                     a = fmaf(l0 * w, c3.x, a); bb = fmaf(l0 * w, c3.y, bb);
        w = m1 * l2; a = fmaf(m0 * w, c4.x, a); bb = fmaf(m0 * w, c4.y, bb);
                     a = fmaf(l0 * w, c5.x, a); bb = fmaf(l0 * w, c5.y, bb);
        w = l1 * l2; a = fmaf(m0 * w, c6.x, a); bb = fmaf(m0 * w, c6.y, bb);
                     a = fmaf(l0 * w, c7.x, a); bb = fmaf(l0 * w, c7.y, bb);
    }

    feats[(size_t)l * NPTS + pt] = (uint_t)f2bf(a) | ((uint_t)f2bf(bb) << 16);
}

// ---------------- Kernel B: MFMA MLPs — ONE WAVE PER BLOCK ----------------
// Each wave's 64-point tile is self-contained; with 64-thread blocks the
// barriers degenerate to waitcnt drains and ~16 independent blocks/CU
// overlap LDS/MFMA/global chains (vs 4 lockstep 4-wave blocks before).
extern "C" __global__ void __launch_bounds__(64) ngp_mlp(
    const float* __restrict__ xin, const float* __restrict__ din,
    const uint_t* __restrict__ featsbf, const ushort_t* __restrict__ wf,
    const float* __restrict__ db1, const float* __restrict__ db2,
    const float* __restrict__ cb1, const float* __restrict__ cb2,
    const float* __restrict__ cb3,
    float* __restrict__ out)
{
    __shared__ short act[4096];
    __shared__ float mk[64];

    const int lane = (int)threadIdx.x;
    const int lrow = lane & 15;
    const int lq   = lane >> 4;
    const int ptb  = blockIdx.x * 64;
    const int p    = ptb + lane;
    char* Ab = (char*)&act[0];

#define LDSA(mt, kc) (*reinterpret_cast<const short8*>(Ab + ((((mt) * 16 + lrow) * 128 + (kc) * 64 + lq * 16) ^ ((lrow & 7) << 4))))
#define LOADB(off)   (*reinterpret_cast<const short8*>(wf + (off) + lane * 8))
#define STB16(row, col, val) *reinterpret_cast<ushort_t*>(Ab + ((((row) * 128 + (col) * 2)) ^ (((row) & 7) << 4))) = (val)

    const float x0 = xin[3 * p + 0];
    const float x1 = xin[3 * p + 1];
    const float x2 = xin[3 * p + 2];
    const bool msk = (fabsf(x0) < 1.5f) & (fabsf(x1) < 1.5f) & (fabsf(x2) < 1.5f);
    mk[lane] = msk ? 1.0f : 0.0f;

    uint_t u[16];
    #pragma unroll
    for (int l = 0; l < 16; ++l) u[l] = featsbf[(size_t)l * NPTS + p];
    #pragma unroll
    for (int c = 0; c < 4; ++c) {
        short8 v;
        #pragma unroll
        for (int q = 0; q < 4; ++q) {
            v[2 * q + 0] = (short)(u[4 * c + q] & 0xFFFFu);
            v[2 * q + 1] = (short)(u[4 * c + q] >> 16);
        }
        const int byte = (lane * 128 + 16 * c) ^ ((lane & 7) << 4);
        *reinterpret_cast<short8*>(Ab + byte) = v;
    }
    const float d0v = din[3 * p + 0];
    const float d1v = din[3 * p + 1];
    const float d2v = din[3 * p + 2];

    __syncthreads();

    // ---- Layer D1: feats[64x32] @ dW1[32x64] ----
    f32x4 acc[4][4];
    #pragma unroll
    for (int nt = 0; nt < 4; ++nt) {
        const float b = db1[nt * 16 + lrow];
        #pragma unroll
        for (int mt = 0; mt < 4; ++mt) acc[mt][nt] = (f32x4){b, b, b, b};
    }
    {
        short8 a0 = LDSA(0, 0), a1 = LDSA(1, 0), a2 = LDSA(2, 0), a3 = LDSA(3, 0);
        #pragma unroll
        for (int nt = 0; nt < 4; ++nt) {
            const short8 B = LOADB(OFF_DW1 + nt * 512);
            acc[0][nt] = MFMA(a0, B, acc[0][nt]);
            acc[1][nt] = MFMA(a1, B, acc[1][nt]);
            acc[2][nt] = MFMA(a2, B, acc[2][nt]);
            acc[3][nt] = MFMA(a3, B, acc[3][nt]);
        }
    }
    __syncthreads();
    #pragma unroll
    for (int mt = 0; mt < 4; ++mt)
        #pragma unroll
        for (int nt = 0; nt < 4; ++nt)
            #pragma unroll
            for (int r = 0; r < 4; ++r) {
                const int row = mt * 16 + lq * 4 + r;
                STB16(row, nt * 16 + lrow, f2bf(fmaxf(acc[mt][nt][r], 0.0f)));
            }
    __syncthreads();

    // ---- Layer D2: hid[64x64] @ dW2[64x16] ----
    f32x4 hD[4];
    {
        const float b = db2[lrow];
        #pragma unroll
        for (int mt = 0; mt < 4; ++mt) hD[mt] = (f32x4){b, b, b, b};
        #pragma unroll
        for (int kc = 0; kc < 2; ++kc) {
            const short8 B = LOADB(OFF_DW2 + kc * 512);
            #pragma unroll
            for (int mt = 0; mt < 4; ++mt) hD[mt] = MFMA(LDSA(mt, kc), B, hD[mt]);
        }
    }
    __syncthreads();

    if (lrow == 0) {
        #pragma unroll
        for (int mt = 0; mt < 4; ++mt)
            #pragma unroll
            for (int r = 0; r < 4; ++r) {
                const int row = mt * 16 + lq * 4 + r;
                out[3 * NPTS + ptb + row] = (mk[row] != 0.0f) ? __expf(hD[mt][r]) : 0.0f;
            }
    }
    #pragma unroll
    for (int mt = 0; mt < 4; ++mt)
        #pragma unroll
        for (int r = 0; r < 4; ++r) {
            const int row = mt * 16 + lq * 4 + r;
            STB16(row, lrow, f2bf(hD[mt][r]));
        }
    {
        ushort_t t[48];
        t[0] = f2bf(d0v); t[1] = f2bf(d1v); t[2] = f2bf(d2v);
        #pragma unroll
        for (int j = 0; j < 4; ++j) {
            const float s = (float)(1 << j);
            t[3 + 6 * j + 0] = f2bf(__sinf(s * d0v));
            t[3 + 6 * j + 1] = f2bf(__sinf(s * d1v));
            t[3 + 6 * j + 2] = f2bf(__sinf(s * d2v));
            t[3 + 6 * j + 3] = f2bf(__cosf(s * d0v));
            t[3 + 6 * j + 4] = f2bf(__cosf(s * d1v));
            t[3 + 6 * j + 5] = f2bf(__cosf(s * d2v));
        }
        #pragma unroll
        for (int i = 27; i < 48; ++i) t[i] = 0;
        #pragma unroll
        for (int c = 0; c < 6; ++c) {
            short8 v;
            #pragma unroll
            for (int j = 0; j < 8; ++j) v[j] = (short)t[8 * c + j];
            const int byte = (lane * 128 + 32 + 16 * c) ^ ((lane & 7) << 4);
            *reinterpret_cast<short8*>(Ab + byte) = v;
        }
    }
    __syncthreads();

    // ---- Layer C1: ch[64x64(43)] @ cW1[64x64] ----
    #pragma unroll
    for (int nt = 0; nt < 4; ++nt) {
        const float b = cb1[nt * 16 + lrow];
        #pragma unroll
        for (int mt = 0; mt < 4; ++mt) acc[mt][nt] = (f32x4){b, b, b, b};
    }
    #pragma unroll
    for (int kc = 0; kc < 2; ++kc) {
        short8 a0 = LDSA(0, kc), a1 = LDSA(1, kc), a2 = LDSA(2, kc), a3 = LDSA(3, kc);
        #pragma unroll
        for (int nt = 0; nt < 4; ++nt) {
            const short8 B = LOADB(OFF_CW1 + (kc * 4 + nt) * 512);
            acc[0][nt] = MFMA(a0, B, acc[0][nt]);
            acc[1][nt] = MFMA(a1, B, acc[1][nt]);
            acc[2][nt] = MFMA(a2, B, acc[2][nt]);
            acc[3][nt] = MFMA(a3, B, acc[3][nt]);
        }
    }
    __syncthreads();
    #pragma unroll
    for (int mt = 0; mt < 4; ++mt)
        #pragma unroll
        for (int nt = 0; nt < 4; ++nt)
            #pragma unroll
            for (int r = 0; r < 4; ++r) {
                const int row = mt * 16 + lq * 4 + r;
                STB16(row, nt * 16 + lrow, f2bf(fmaxf(acc[mt][nt][r], 0.0f)));
            }
    __syncthreads();

    // ---- Layer C2: c1[64x64] @ cW2[64x64] ----
    #pragma unroll
    for (int nt = 0; nt < 4; ++nt) {
        const float b = cb2[nt * 16 + lrow];
        #pragma unroll
        for (int mt = 0; mt < 4; ++mt) acc[mt][nt] = (f32x4){b, b, b, b};
    }
    #pragma unroll
    for (int kc = 0; kc < 2; ++kc) {
        short8 a0 = LDSA(0, kc), a1 = LDSA(1, kc), a2 = LDSA(2, kc), a3 = LDSA(3, kc);
        #pragma unroll
        for (int nt = 0; nt < 4; ++nt) {
            const short8 B = LOADB(OFF_CW2 + (kc * 4 + nt) * 512);
            acc[0][nt] = MFMA(a0, B, acc[0][nt]);
            acc[1][nt] = MFMA(a1, B, acc[1][nt]);
            acc[2][nt] = MFMA(a2, B, acc[2][nt]);
            acc[3][nt] = MFMA(a3, B, acc[3][nt]);
        }
    }
    __syncthreads();
    #pragma unroll
    for (int mt = 0; mt < 4; ++mt)
        #pragma unroll
        for (int nt = 0; nt < 4; ++nt)
            #pragma unroll
            for (int r = 0; r < 4; ++r) {
                const int row = mt * 16 + lq * 4 + r;
                STB16(row, nt * 16 + lrow, f2bf(fmaxf(acc[mt][nt][r], 0.0f)));
            }
    __syncthreads();

    // ---- Layer C3: c2[64x64] @ cW3[64x3(pad16)] ----
    f32x4 rD[4];
    {
        const float b = (lrow < 3) ? cb3[lrow] : 0.0f;
        #pragma unroll
        for (int mt = 0; mt < 4; ++mt) rD[mt] = (f32x4){b, b, b, b};
        #pragma unroll
        for (int kc = 0; kc < 2; ++kc) {
            const short8 B = LOADB(OFF_CW3 + kc * 512);
            #pragma unroll
            for (int mt = 0; mt < 4; ++mt) rD[mt] = MFMA(LDSA(mt, kc), B, rD[mt]);
        }
    }
    if (lrow < 3) {
        #pragma unroll
        for (int mt = 0; mt < 4; ++mt)
            #pragma unroll
            for (int r = 0; r < 4; ++r) {
                const int row = mt * 16 + lq * 4 + r;
                out[3 * (ptb + row) + lrow] = (mk[row] != 0.0f) ? sigmoidf_fast(rD[mt][r]) : 0.0f;
            }
    }
#undef LDSA
#undef LOADB
#undef STB16
}

extern "C" void kernel_launch(void* const* d_in, const int* in_sizes, int n_in,
                              void* d_out, int out_size, void* d_ws, size_t ws_size,
                              hipStream_t stream) {
    const float* x    = (const float*)d_in[0];
    const float* d    = (const float*)d_in[1];
    const float* tbl  = (const float*)d_in[2];
    const float* dW1  = (const float*)d_in[3];
    const float* db1  = (const float*)d_in[4];
    const float* dW2  = (const float*)d_in[5];
    const float* db2  = (const float*)d_in[6];
    const float* cW1  = (const float*)d_in[7];
    const float* cb1  = (const float*)d_in[8];
    const float* cW2  = (const float*)d_in[9];
    const float* cb2  = (const float*)d_in[10];
    const float* cW3  = (const float*)d_in[11];
    const float* cb3  = (const float*)d_in[12];

    uint_t* feats = (uint_t*)d_ws;                               // 16 MB
    f32x4* dense  = (f32x4*)((char*)d_ws + WS_DN_OFF);           // 5.31 MB
    ushort_t* wfr = (ushort_t*)((char*)d_ws + WS_WF_OFF);        // 24 KB

    ngp_predense<<<PREP_BLOCKS + DENSE_BLOCKS, 256, 0, stream>>>(
        dW1, dW2, cW1, cW2, cW3, wfr, tbl, dense);
    ngp_encode<<<16 * 1024, 256, 0, stream>>>(x, tbl, dense, feats);
    ngp_mlp<<<NPTS / 64, 64, 0, stream>>>(
        x, d, feats, wfr, db1, db2, cb1, cb2, cb3, (float*)d_out);
}